// Round 4
// baseline (170.609 us; speedup 1.0000x reference)
//
#include <hip/hip_runtime.h>
#include <hip/hip_bf16.h>
#include <cmath>

// ---------------------------------------------------------------------------
// DistanceAwareSelfAttentionHead — bf16 MFMA, round 4.
//   - PV: single-pass 128x64-tile GEMM (grid 8x32=256 blocks), rank-2 epilogue
//     fused into the C-write (no partials, no reduce kernel)
//   - one fused prep kernel (x->bf16, Wq|Wk transpose, Wv transpose)
//   - c0/c1 zeroing folded into node_dots
//   9 kernel launches total.
// ---------------------------------------------------------------------------

typedef short bf16x8 __attribute__((ext_vector_type(8)));
typedef float f32x4  __attribute__((ext_vector_type(4)));
typedef unsigned short ushort_t;
typedef unsigned short ushort4v __attribute__((ext_vector_type(4)));
typedef unsigned short ushort8v __attribute__((ext_vector_type(8)));

__device__ __forceinline__ ushort_t f2bf(float f) {
    union { float f; unsigned u; } v; v.f = f;
    unsigned u = v.u;
    u += 0x7FFFu + ((u >> 16) & 1u);   // RNE
    return (ushort_t)(u >> 16);
}
__device__ __forceinline__ float bf2f(ushort_t h) {
    union { unsigned u; float f; } v; v.u = ((unsigned)h) << 16;
    return v.f;
}
__device__ __forceinline__ void gload_lds16(const void* g, void* l) {
    __builtin_amdgcn_global_load_lds(
        (const __attribute__((address_space(1))) void*)g,
        (__attribute__((address_space(3))) void*)l, 16, 0, 0);
}

// ---------------------------------------------------------------------------
// NT bf16 GEMM: C[m][n] = alpha * sum_k A[m][k] * B[n][k]
// 128x128 tile, 4 waves 2x2. Grid (x = Nout/128, y = M/128).
// ---------------------------------------------------------------------------
template<bool STORE_BF16>
__global__ __launch_bounds__(256) void gemm_nt_mfma(
    const ushort_t* __restrict__ A, const ushort_t* __restrict__ B,
    void* __restrict__ Cv, int lda, int ldb, int ldc, int Ksz, float alpha)
{
    constexpr int BK = 32;
    __shared__ ushort_t As[128 * BK];
    __shared__ ushort_t Bs[128 * BK];

    int bid = blockIdx.y * gridDim.x + blockIdx.x;
    const int nwg = gridDim.x * gridDim.y;
    if ((nwg & 7) == 0) {
        const int cpx = nwg >> 3;
        bid = (bid & 7) * cpx + (bid >> 3);
    }
    const int bm = (bid / gridDim.x) * 128;
    const int bn = (bid % gridDim.x) * 128;

    const int tid  = threadIdx.x;
    const int lane = tid & 63;
    const int wid  = tid >> 6;
    const int wm = (wid >> 1) * 64;
    const int wn = (wid & 1) * 64;

    f32x4 acc[4][4] = {};

    const int r0 = tid >> 2;
    const int c8 = (tid & 3) * 8;
    const ushort_t* Ag0 = A + (size_t)(bm + r0) * lda + c8;
    const ushort_t* Bg0 = B + (size_t)(bn + r0) * ldb + c8;
    const ushort_t* Ag1 = Ag0 + (size_t)64 * lda;
    const ushort_t* Bg1 = Bg0 + (size_t)64 * ldb;
    ushort_t* AsW0 = &As[(wid * 64) * 8];
    ushort_t* AsW1 = &As[(256 + wid * 64) * 8];
    ushort_t* BsW0 = &Bs[(wid * 64) * 8];
    ushort_t* BsW1 = &Bs[(256 + wid * 64) * 8];

    const int fr = lane & 15;
    const int kh = (lane >> 4) * 8;

    for (int k0 = 0; k0 < Ksz; k0 += BK) {
        gload_lds16(Ag0 + k0, AsW0);
        gload_lds16(Ag1 + k0, AsW1);
        gload_lds16(Bg0 + k0, BsW0);
        gload_lds16(Bg1 + k0, BsW1);
        __syncthreads();

        bf16x8 af[4], bfv[4];
        #pragma unroll
        for (int i = 0; i < 4; ++i) {
            af[i]  = *(const bf16x8*)&As[(wm + i * 16 + fr) * BK + kh];
            bfv[i] = *(const bf16x8*)&Bs[(wn + i * 16 + fr) * BK + kh];
        }
        #pragma unroll
        for (int i = 0; i < 4; ++i)
            #pragma unroll
            for (int j = 0; j < 4; ++j)
                acc[i][j] = __builtin_amdgcn_mfma_f32_16x16x32_bf16(
                    af[i], bfv[j], acc[i][j], 0, 0, 0);
        __syncthreads();
    }

    const int cr = (lane >> 4) * 4;
    const int cc = lane & 15;
    #pragma unroll
    for (int i = 0; i < 4; ++i)
        #pragma unroll
        for (int j = 0; j < 4; ++j) {
            const int col = bn + wn + j * 16 + cc;
            const int rowb = bm + wm + i * 16 + cr;
            #pragma unroll
            for (int jj = 0; jj < 4; ++jj) {
                const float val = alpha * acc[i][j][jj];
                if (STORE_BF16)
                    ((ushort_t*)Cv)[(size_t)(rowb + jj) * ldc + col] = f2bf(val);
                else
                    ((float*)Cv)[(size_t)(rowb + jj) * ldc + col] = val;
            }
        }
}

// ---------------------------------------------------------------------------
// PV GEMM: out[m][f] = sum_k P[m][k] * vT[f][k] + c0[m]*Ev[f] + c1[m]*Ev[FEAT+f]
// BM=128, BN=64, 4 waves 2x2 (wave tile 64x32). Grid (FEAT/64, M/128).
// ---------------------------------------------------------------------------
__global__ __launch_bounds__(256) void pv_gemm(
    const ushort_t* __restrict__ P, const ushort_t* __restrict__ vT,
    float* __restrict__ out,
    const float* __restrict__ c0, const float* __restrict__ c1,
    const float* __restrict__ Ev, int N, int FEAT)
{
    constexpr int BK = 32;
    __shared__ ushort_t As[128 * BK];   // P tile 128 x 32
    __shared__ ushort_t Bs[64 * BK];    // vT tile 64 x 32

    int bid = blockIdx.y * gridDim.x + blockIdx.x;
    const int nwg = gridDim.x * gridDim.y;
    if ((nwg & 7) == 0) {
        const int cpx = nwg >> 3;
        bid = (bid & 7) * cpx + (bid >> 3);
    }
    const int bm = (bid / gridDim.x) * 128;
    const int bn = (bid % gridDim.x) * 64;

    const int tid  = threadIdx.x;
    const int lane = tid & 63;
    const int wid  = tid >> 6;
    const int wm = (wid >> 1) * 64;    // rows
    const int wn = (wid & 1) * 32;     // cols

    f32x4 acc[4][2] = {};

    const int r0 = tid >> 2;           // 0..63
    const int c8 = (tid & 3) * 8;
    const ushort_t* Ag0 = P  + (size_t)(bm + r0) * N + c8;
    const ushort_t* Ag1 = Ag0 + (size_t)64 * N;
    const ushort_t* Bg0 = vT + (size_t)(bn + r0) * N + c8;
    ushort_t* AsW0 = &As[(wid * 64) * 8];
    ushort_t* AsW1 = &As[(256 + wid * 64) * 8];
    ushort_t* BsW0 = &Bs[(wid * 64) * 8];   // wave w -> rows 16w..16w+15

    const int fr = lane & 15;
    const int kh = (lane >> 4) * 8;

    for (int k0 = 0; k0 < N; k0 += BK) {
        gload_lds16(Ag0 + k0, AsW0);
        gload_lds16(Ag1 + k0, AsW1);
        gload_lds16(Bg0 + k0, BsW0);
        __syncthreads();

        bf16x8 af[4], bfv[2];
        #pragma unroll
        for (int i = 0; i < 4; ++i)
            af[i]  = *(const bf16x8*)&As[(wm + i * 16 + fr) * BK + kh];
        #pragma unroll
        for (int j = 0; j < 2; ++j)
            bfv[j] = *(const bf16x8*)&Bs[(wn + j * 16 + fr) * BK + kh];
        #pragma unroll
        for (int i = 0; i < 4; ++i)
            #pragma unroll
            for (int j = 0; j < 2; ++j)
                acc[i][j] = __builtin_amdgcn_mfma_f32_16x16x32_bf16(
                    af[i], bfv[j], acc[i][j], 0, 0, 0);
        __syncthreads();
    }

    const int cr = (lane >> 4) * 4;
    const int cc = lane & 15;
    #pragma unroll
    for (int i = 0; i < 4; ++i) {
        const int rowb = bm + wm + i * 16 + cr;
        #pragma unroll
        for (int j = 0; j < 2; ++j) {
            const int col = bn + wn + j * 16 + cc;
            const float e0 = Ev[col], e1 = Ev[FEAT + col];
            #pragma unroll
            for (int jj = 0; jj < 4; ++jj) {
                const int row = rowb + jj;
                out[(size_t)row * FEAT + col] =
                    acc[i][j][jj] + c0[row] * e0 + c1[row] * e1;
            }
        }
    }
}

// ---------------------------------------------------------------------------
// prep: xb = bf16(x); Wqkt[o][i] = bf16(Wq/Wk[i][o]); Wvt[o][i] = bf16(Wv[i][o])
__global__ __launch_bounds__(256) void prep_kernel(
    const float* __restrict__ x, const float* __restrict__ Wq,
    const float* __restrict__ Wk, const float* __restrict__ Wv,
    ushort_t* __restrict__ xb, ushort_t* __restrict__ Wqkt,
    ushort_t* __restrict__ Wvt, int N, int FEAT, int HID)
{
    const int xBlocks = (N * FEAT / 8) / 256;     // 1024
    const int wBlocks = (HID * FEAT) / 256;       // 512
    const int b = blockIdx.x;
    if (b < xBlocks) {
        const int i = b * 256 + threadIdx.x;
        const float4 a = ((const float4*)x)[2 * i];
        const float4 c = ((const float4*)x)[2 * i + 1];
        ushort8v o;
        o[0] = f2bf(a.x); o[1] = f2bf(a.y); o[2] = f2bf(a.z); o[3] = f2bf(a.w);
        o[4] = f2bf(c.x); o[5] = f2bf(c.y); o[6] = f2bf(c.z); o[7] = f2bf(c.w);
        ((ushort8v*)xb)[i] = o;
    } else if (b < xBlocks + wBlocks) {
        const int idx = (b - xBlocks) * 256 + threadIdx.x;
        const int o = idx / FEAT, i = idx % FEAT;
        Wqkt[idx] = f2bf(Wq[(size_t)i * HID + o]);
    } else if (b < xBlocks + 2 * wBlocks) {
        const int idx = (b - xBlocks - wBlocks) * 256 + threadIdx.x;
        const int o = idx / FEAT, i = idx % FEAT;
        Wqkt[(size_t)HID * FEAT + idx] = f2bf(Wk[(size_t)i * HID + o]);
    } else {
        const int idx = (b - xBlocks - 2 * wBlocks) * 256 + threadIdx.x;
        const int o = idx / FEAT, i = idx % FEAT;
        Wvt[idx] = f2bf(Wv[(size_t)i * FEAT + o]);
    }
}

// per-node dots from merged qk buffer; also zeroes c0/c1
__global__ __launch_bounds__(256) void node_dots(
    const ushort_t* __restrict__ qk,
    const float* __restrict__ Ek, const float* __restrict__ Eq,
    float* qk0, float* qk1, float* kq0, float* kq1,
    float* c0, float* c1, int HID)
{
    const int node = blockIdx.x;
    const int t = threadIdx.x;   // == HID == 256
    const ushort_t* row = qk + (size_t)node * (2 * HID);
    const float qv = bf2f(row[t]);
    const float kv = bf2f(row[HID + t]);
    float p0 = qv * Ek[t];
    float p1 = qv * Ek[HID + t];
    float p2 = kv * Eq[t];
    float p3 = kv * Eq[HID + t];
    #pragma unroll
    for (int off = 32; off > 0; off >>= 1) {
        p0 += __shfl_down(p0, off);
        p1 += __shfl_down(p1, off);
        p2 += __shfl_down(p2, off);
        p3 += __shfl_down(p3, off);
    }
    __shared__ float red[4][4];
    if ((t & 63) == 0) {
        const int w = t >> 6;
        red[w][0] = p0; red[w][1] = p1; red[w][2] = p2; red[w][3] = p3;
    }
    __syncthreads();
    if (t == 0) {
        qk0[node] = red[0][0] + red[1][0] + red[2][0] + red[3][0];
        qk1[node] = red[0][1] + red[1][1] + red[2][1] + red[3][1];
        kq0[node] = red[0][2] + red[1][2] + red[2][2] + red[3][2];
        kq1[node] = red[0][3] + red[1][3] + red[2][3] + red[3][3];
        c0[node] = 0.f;
        c1[node] = 0.f;
    }
}

__global__ void edge_bias_kernel(
    const int* __restrict__ ei, const float* __restrict__ attr,
    const float* __restrict__ qk0, const float* __restrict__ qk1,
    const float* __restrict__ kq0, const float* __restrict__ kq1,
    float* __restrict__ A, int E, int N,
    const float* __restrict__ ibp, const float* __restrict__ imp)
{
    const int e = blockIdx.x * blockDim.x + threadIdx.x;
    if (e >= E) return;
    const int src = ei[e];
    const int dst = ei[E + e];
    const float s = 1.f / (1.f + __expf(-(attr[e] - ibp[0]) * imp[0]));
    const float bias = s * qk0[src] + (1.f - s) * qk1[src]
                     + s * kq0[dst] + (1.f - s) * kq1[dst];
    atomicAdd(&A[(size_t)src * N + dst], bias);
}

// row softmax: read f32 logits, write bf16 probs. N==4096, 256 threads.
__global__ __launch_bounds__(256) void softmax_rows_bf16(
    const float* __restrict__ A, ushort_t* __restrict__ P, int N, float scale)
{
    const int row = blockIdx.x;
    const float* a = A + (size_t)row * N;
    ushort_t* p = P + (size_t)row * N;
    const int t = threadIdx.x;
    float4 vals[4];
    float mx = -1e30f;
    #pragma unroll
    for (int u = 0; u < 4; ++u) {
        float4 vv = ((const float4*)a)[t + u * 256];
        vv.x *= scale; vv.y *= scale; vv.z *= scale; vv.w *= scale;
        vals[u] = vv;
        mx = fmaxf(mx, fmaxf(fmaxf(vv.x, vv.y), fmaxf(vv.z, vv.w)));
    }
    __shared__ float red[4];
    #pragma unroll
    for (int off = 32; off > 0; off >>= 1) mx = fmaxf(mx, __shfl_down(mx, off));
    if ((t & 63) == 0) red[t >> 6] = mx;
    __syncthreads();
    const float m = fmaxf(fmaxf(red[0], red[1]), fmaxf(red[2], red[3]));
    __syncthreads();
    float sum = 0.f;
    #pragma unroll
    for (int u = 0; u < 4; ++u) {
        vals[u].x = __expf(vals[u].x - m);
        vals[u].y = __expf(vals[u].y - m);
        vals[u].z = __expf(vals[u].z - m);
        vals[u].w = __expf(vals[u].w - m);
        sum += vals[u].x + vals[u].y + vals[u].z + vals[u].w;
    }
    #pragma unroll
    for (int off = 32; off > 0; off >>= 1) sum += __shfl_down(sum, off);
    if ((t & 63) == 0) red[t >> 6] = sum;
    __syncthreads();
    const float inv = 1.f / (red[0] + red[1] + red[2] + red[3]);
    #pragma unroll
    for (int u = 0; u < 4; ++u) {
        ushort4v o;
        o[0] = f2bf(vals[u].x * inv);
        o[1] = f2bf(vals[u].y * inv);
        o[2] = f2bf(vals[u].z * inv);
        o[3] = f2bf(vals[u].w * inv);
        ((ushort4v*)p)[t + u * 256] = o;
    }
}

__global__ void edge_coeff_kernel(
    const int* __restrict__ ei, const float* __restrict__ attr,
    const ushort_t* __restrict__ P, float* __restrict__ c0, float* __restrict__ c1,
    int E, int N, const float* __restrict__ ibp, const float* __restrict__ imp)
{
    const int e = blockIdx.x * blockDim.x + threadIdx.x;
    if (e >= E) return;
    const int src = ei[e];
    const int dst = ei[E + e];
    const float s = 1.f / (1.f + __expf(-(attr[e] - ibp[0]) * imp[0]));
    const float pv = bf2f(P[(size_t)src * N + dst]);
    atomicAdd(&c0[src], pv * s);
    atomicAdd(&c1[src], pv * (1.f - s));
}

// ---------------------------------------------------------------------------
extern "C" void kernel_launch(void* const* d_in, const int* in_sizes, int n_in,
                              void* d_out, int out_size, void* d_ws, size_t ws_size,
                              hipStream_t stream)
{
    const float* x    = (const float*)d_in[0];
    const int*   ei   = (const int*)d_in[1];
    const float* attr = (const float*)d_in[2];
    const float* Wk   = (const float*)d_in[3];
    const float* Wq   = (const float*)d_in[4];
    const float* Wv   = (const float*)d_in[5];
    const float* Ek   = (const float*)d_in[6];
    const float* Eq   = (const float*)d_in[7];
    const float* Ev   = (const float*)d_in[8];
    const float* ib   = (const float*)d_in[9];
    const float* im   = (const float*)d_in[10];
    float* out = (float*)d_out;

    const int FEAT = (int)lroundf(sqrtf((float)in_sizes[5]));   // 512
    const int HID  = in_sizes[3] / FEAT;                        // 256
    const int N    = in_sizes[0] / FEAT;                        // 4096
    const int E    = in_sizes[2];                               // 131072

    char* w = (char*)d_ws;
    size_t o = 0;
    ushort_t* xb   = (ushort_t*)(w + o); o += (size_t)N * FEAT * 2;
    ushort_t* Wqkt = (ushort_t*)(w + o); o += (size_t)2 * HID * FEAT * 2;
    ushort_t* Wvt  = (ushort_t*)(w + o); o += (size_t)FEAT * FEAT * 2;
    ushort_t* qkb  = (ushort_t*)(w + o); o += (size_t)N * 2 * HID * 2;
    ushort_t* vTb  = (ushort_t*)(w + o); o += (size_t)FEAT * N * 2;
    float*    Abuf = (float*)(w + o);    o += (size_t)N * N * 4;
    ushort_t* Pb   = (ushort_t*)(w + o); o += (size_t)N * N * 2;
    float*    qk0  = (float*)(w + o);    o += (size_t)N * 4;
    float*    qk1  = (float*)(w + o);    o += (size_t)N * 4;
    float*    kq0  = (float*)(w + o);    o += (size_t)N * 4;
    float*    kq1  = (float*)(w + o);    o += (size_t)N * 4;
    float*    c0   = (float*)(w + o);    o += (size_t)N * 4;
    float*    c1   = (float*)(w + o);    o += (size_t)N * 4;

    const dim3 blk(256);

    // prep: x->bf16, W transposes (one launch)
    const int prepBlocks = (N * FEAT / 8) / 256 + 2 * ((HID * FEAT) / 256)
                         + (FEAT * FEAT) / 256;
    prep_kernel<<<prepBlocks, blk, 0, stream>>>(x, Wq, Wk, Wv, xb, Wqkt, Wvt,
                                                N, FEAT, HID);

    // merged q|k projection: qkb[N][2*HID] = xb @ Wqkt^T
    gemm_nt_mfma<true><<<dim3(2 * HID / 128, N / 128), blk, 0, stream>>>(
        xb, Wqkt, qkb, FEAT, FEAT, 2 * HID, FEAT, 1.f);
    // vT projection: vTb[FEAT][N] = Wvt @ xb^T
    gemm_nt_mfma<true><<<dim3(N / 128, FEAT / 128), blk, 0, stream>>>(
        Wvt, xb, vTb, FEAT, FEAT, N, FEAT, 1.f);

    // per-node embedding dots (+ c0/c1 zero)
    node_dots<<<N, blk, 0, stream>>>(qkb, Ek, Eq, qk0, qk1, kq0, kq1, c0, c1, HID);

    // A = 2 * q k^T  (f32)
    gemm_nt_mfma<false><<<dim3(N / 128, N / 128), blk, 0, stream>>>(
        qkb, qkb + HID, Abuf, 2 * HID, 2 * HID, N, HID, 2.f);

    // += per-edge bias
    edge_bias_kernel<<<(E + 255) / 256, blk, 0, stream>>>(ei, attr, qk0, qk1, kq0, kq1,
                                                          Abuf, E, N, ib, im);

    // P = softmax(A / sqrt(FEAT)) -> bf16
    softmax_rows_bf16<<<N, blk, 0, stream>>>(Abuf, Pb, N, 1.f / sqrtf((float)FEAT));

    // edge coefficients
    edge_coeff_kernel<<<(E + 255) / 256, blk, 0, stream>>>(ei, attr, Pb, c0, c1, E, N, ib, im);

    // out = P @ v + c0*Ev0 + c1*Ev1  (fused epilogue)
    pv_gemm<<<dim3(FEAT / 64, N / 128), blk, 0, stream>>>(Pb, vTb, out, c0, c1, Ev, N, FEAT);
}

// Round 5
// 132.703 us; speedup vs baseline: 1.2856x; 1.2856x over previous
//
#include <hip/hip_runtime.h>
#include <hip/hip_bf16.h>
#include <cmath>

// ---------------------------------------------------------------------------
// DistanceAwareSelfAttentionHead — bf16 MFMA, round 5.
//   - PV: split-K NZ=4 (512 blocks, 2/CU — proven round 3), partials alias
//     dead Abuf, rank-2 epilogue fused into reduce kernel
//   - both projection GEMMs merged into ONE 256-block launch
//   - fused prep kernel; c0/c1 zeroing inside node_dots
//   9 kernel launches.
// ---------------------------------------------------------------------------

typedef short bf16x8 __attribute__((ext_vector_type(8)));
typedef float f32x4  __attribute__((ext_vector_type(4)));
typedef unsigned short ushort_t;
typedef unsigned short ushort4v __attribute__((ext_vector_type(4)));
typedef unsigned short ushort8v __attribute__((ext_vector_type(8)));

__device__ __forceinline__ ushort_t f2bf(float f) {
    union { float f; unsigned u; } v; v.f = f;
    unsigned u = v.u;
    u += 0x7FFFu + ((u >> 16) & 1u);   // RNE
    return (ushort_t)(u >> 16);
}
__device__ __forceinline__ float bf2f(ushort_t h) {
    union { unsigned u; float f; } v; v.u = ((unsigned)h) << 16;
    return v.f;
}
__device__ __forceinline__ void gload_lds16(const void* g, void* l) {
    __builtin_amdgcn_global_load_lds(
        (const __attribute__((address_space(1))) void*)g,
        (__attribute__((address_space(3))) void*)l, 16, 0, 0);
}

// ---------------------------------------------------------------------------
// Shared 128x128x(BK=32) NT GEMM body. C[m][n] = alpha*sum_k A[m][k]*B[n][k].
// ---------------------------------------------------------------------------
template<bool STORE_BF16>
__device__ __forceinline__ void gemm_body_nt(
    const ushort_t* __restrict__ A, const ushort_t* __restrict__ B,
    void* __restrict__ Cv, int lda, int ldb, int ldc, int Ksz, float alpha,
    int bm, int bn, size_t kbase, ushort_t* As, ushort_t* Bs)
{
    constexpr int BK = 32;
    const int tid  = threadIdx.x;
    const int lane = tid & 63;
    const int wid  = tid >> 6;
    const int wm = (wid >> 1) * 64;
    const int wn = (wid & 1) * 64;

    f32x4 acc[4][4] = {};

    const int r0 = tid >> 2;
    const int c8 = (tid & 3) * 8;
    const ushort_t* Ag0 = A + (size_t)(bm + r0) * lda + kbase + c8;
    const ushort_t* Bg0 = B + (size_t)(bn + r0) * ldb + kbase + c8;
    const ushort_t* Ag1 = Ag0 + (size_t)64 * lda;
    const ushort_t* Bg1 = Bg0 + (size_t)64 * ldb;
    ushort_t* AsW0 = &As[(wid * 64) * 8];
    ushort_t* AsW1 = &As[(256 + wid * 64) * 8];
    ushort_t* BsW0 = &Bs[(wid * 64) * 8];
    ushort_t* BsW1 = &Bs[(256 + wid * 64) * 8];

    const int fr = lane & 15;
    const int kh = (lane >> 4) * 8;

    for (int k0 = 0; k0 < Ksz; k0 += BK) {
        gload_lds16(Ag0 + k0, AsW0);
        gload_lds16(Ag1 + k0, AsW1);
        gload_lds16(Bg0 + k0, BsW0);
        gload_lds16(Bg1 + k0, BsW1);
        __syncthreads();

        bf16x8 af[4], bfv[4];
        #pragma unroll
        for (int i = 0; i < 4; ++i) {
            af[i]  = *(const bf16x8*)&As[(wm + i * 16 + fr) * 32 + kh];
            bfv[i] = *(const bf16x8*)&Bs[(wn + i * 16 + fr) * 32 + kh];
        }
        #pragma unroll
        for (int i = 0; i < 4; ++i)
            #pragma unroll
            for (int j = 0; j < 4; ++j)
                acc[i][j] = __builtin_amdgcn_mfma_f32_16x16x32_bf16(
                    af[i], bfv[j], acc[i][j], 0, 0, 0);
        __syncthreads();
    }

    const int cr = (lane >> 4) * 4;
    const int cc = lane & 15;
    #pragma unroll
    for (int i = 0; i < 4; ++i)
        #pragma unroll
        for (int j = 0; j < 4; ++j) {
            const int col = bn + wn + j * 16 + cc;
            const int rowb = bm + wm + i * 16 + cr;
            #pragma unroll
            for (int jj = 0; jj < 4; ++jj) {
                const float val = alpha * acc[i][j][jj];
                if (STORE_BF16)
                    ((ushort_t*)Cv)[(size_t)(rowb + jj) * ldc + col] = f2bf(val);
                else
                    ((float*)Cv)[(size_t)(rowb + jj) * ldc + col] = val;
            }
        }
}

// general GEMM (XCD swizzle, optional split-K via blockIdx.z / zstride)
template<bool STORE_BF16>
__global__ __launch_bounds__(256) void gemm_nt_mfma(
    const ushort_t* __restrict__ A, const ushort_t* __restrict__ B,
    void* __restrict__ Cv, int lda, int ldb, int ldc,
    int Ksz, float alpha, size_t zstride)
{
    __shared__ ushort_t As[128 * 32];
    __shared__ ushort_t Bs[128 * 32];

    int bid = blockIdx.y * gridDim.x + blockIdx.x;
    const int nwg = gridDim.x * gridDim.y;
    if ((nwg & 7) == 0) {
        const int cpx = nwg >> 3;
        bid = (bid & 7) * cpx + (bid >> 3);
    }
    const int bm = (bid / gridDim.x) * 128;
    const int bn = (bid % gridDim.x) * 128;
    const size_t kbase = (size_t)blockIdx.z * Ksz;
    void* Cz = STORE_BF16 ? Cv : (void*)((float*)Cv + (size_t)blockIdx.z * zstride);
    gemm_body_nt<STORE_BF16>(A, B, Cz, lda, ldb, ldc, Ksz, alpha, bm, bn, kbase, As, Bs);
}

// both projections in one launch (256 blocks):
//   blocks [0,128):  qkb[N][2*HID] = xb @ Wqkt^T
//   blocks [128,256): vTb[FEAT][N] = Wvt @ xb^T
__global__ __launch_bounds__(256) void proj_gemm(
    const ushort_t* __restrict__ xb, const ushort_t* __restrict__ Wqkt,
    const ushort_t* __restrict__ Wvt, ushort_t* __restrict__ qkb,
    ushort_t* __restrict__ vTb, int FEAT, int HID, int N)
{
    __shared__ ushort_t As[128 * 32];
    __shared__ ushort_t Bs[128 * 32];
    const int b = blockIdx.x;
    if (b < 128) {
        const int gx = (2 * HID) / 128;              // 4
        const int bm = (b / gx) * 128, bn = (b % gx) * 128;
        gemm_body_nt<true>(xb, Wqkt, qkb, FEAT, FEAT, 2 * HID, FEAT, 1.f,
                           bm, bn, 0, As, Bs);
    } else {
        const int b2 = b - 128;
        const int gx = N / 128;                      // 32
        const int bm = (b2 / gx) * 128, bn = (b2 % gx) * 128;
        gemm_body_nt<true>(Wvt, xb, vTb, FEAT, FEAT, N, FEAT, 1.f,
                           bm, bn, 0, As, Bs);
    }
}

// ---------------------------------------------------------------------------
// prep: xb = bf16(x); Wqkt[o][i] = bf16(Wq/Wk[i][o]); Wvt[o][i] = bf16(Wv[i][o])
__global__ __launch_bounds__(256) void prep_kernel(
    const float* __restrict__ x, const float* __restrict__ Wq,
    const float* __restrict__ Wk, const float* __restrict__ Wv,
    ushort_t* __restrict__ xb, ushort_t* __restrict__ Wqkt,
    ushort_t* __restrict__ Wvt, int N, int FEAT, int HID)
{
    const int xBlocks = (N * FEAT / 8) / 256;
    const int wBlocks = (HID * FEAT) / 256;
    const int b = blockIdx.x;
    if (b < xBlocks) {
        const int i = b * 256 + threadIdx.x;
        const float4 a = ((const float4*)x)[2 * i];
        const float4 c = ((const float4*)x)[2 * i + 1];
        ushort8v o;
        o[0] = f2bf(a.x); o[1] = f2bf(a.y); o[2] = f2bf(a.z); o[3] = f2bf(a.w);
        o[4] = f2bf(c.x); o[5] = f2bf(c.y); o[6] = f2bf(c.z); o[7] = f2bf(c.w);
        ((ushort8v*)xb)[i] = o;
    } else if (b < xBlocks + wBlocks) {
        const int idx = (b - xBlocks) * 256 + threadIdx.x;
        const int o = idx / FEAT, i = idx % FEAT;
        Wqkt[idx] = f2bf(Wq[(size_t)i * HID + o]);
    } else if (b < xBlocks + 2 * wBlocks) {
        const int idx = (b - xBlocks - wBlocks) * 256 + threadIdx.x;
        const int o = idx / FEAT, i = idx % FEAT;
        Wqkt[(size_t)HID * FEAT + idx] = f2bf(Wk[(size_t)i * HID + o]);
    } else {
        const int idx = (b - xBlocks - 2 * wBlocks) * 256 + threadIdx.x;
        const int o = idx / FEAT, i = idx % FEAT;
        Wvt[idx] = f2bf(Wv[(size_t)i * FEAT + o]);
    }
}

// per-node dots from merged qk buffer; also zeroes c0/c1
__global__ __launch_bounds__(256) void node_dots(
    const ushort_t* __restrict__ qk,
    const float* __restrict__ Ek, const float* __restrict__ Eq,
    float* qk0, float* qk1, float* kq0, float* kq1,
    float* c0, float* c1, int HID)
{
    const int node = blockIdx.x;
    const int t = threadIdx.x;   // == HID == 256
    const ushort_t* row = qk + (size_t)node * (2 * HID);
    const float qv = bf2f(row[t]);
    const float kv = bf2f(row[HID + t]);
    float p0 = qv * Ek[t];
    float p1 = qv * Ek[HID + t];
    float p2 = kv * Eq[t];
    float p3 = kv * Eq[HID + t];
    #pragma unroll
    for (int off = 32; off > 0; off >>= 1) {
        p0 += __shfl_down(p0, off);
        p1 += __shfl_down(p1, off);
        p2 += __shfl_down(p2, off);
        p3 += __shfl_down(p3, off);
    }
    __shared__ float red[4][4];
    if ((t & 63) == 0) {
        const int w = t >> 6;
        red[w][0] = p0; red[w][1] = p1; red[w][2] = p2; red[w][3] = p3;
    }
    __syncthreads();
    if (t == 0) {
        qk0[node] = red[0][0] + red[1][0] + red[2][0] + red[3][0];
        qk1[node] = red[0][1] + red[1][1] + red[2][1] + red[3][1];
        kq0[node] = red[0][2] + red[1][2] + red[2][2] + red[3][2];
        kq1[node] = red[0][3] + red[1][3] + red[2][3] + red[3][3];
        c0[node] = 0.f;
        c1[node] = 0.f;
    }
}

__global__ void edge_bias_kernel(
    const int* __restrict__ ei, const float* __restrict__ attr,
    const float* __restrict__ qk0, const float* __restrict__ qk1,
    const float* __restrict__ kq0, const float* __restrict__ kq1,
    float* __restrict__ A, int E, int N,
    const float* __restrict__ ibp, const float* __restrict__ imp)
{
    const int e = blockIdx.x * blockDim.x + threadIdx.x;
    if (e >= E) return;
    const int src = ei[e];
    const int dst = ei[E + e];
    const float s = 1.f / (1.f + __expf(-(attr[e] - ibp[0]) * imp[0]));
    const float bias = s * qk0[src] + (1.f - s) * qk1[src]
                     + s * kq0[dst] + (1.f - s) * kq1[dst];
    atomicAdd(&A[(size_t)src * N + dst], bias);
}

// row softmax: read f32 logits, write bf16 probs. N==4096, 256 threads.
__global__ __launch_bounds__(256) void softmax_rows_bf16(
    const float* __restrict__ A, ushort_t* __restrict__ P, int N, float scale)
{
    const int row = blockIdx.x;
    const float* a = A + (size_t)row * N;
    ushort_t* p = P + (size_t)row * N;
    const int t = threadIdx.x;
    float4 vals[4];
    float mx = -1e30f;
    #pragma unroll
    for (int u = 0; u < 4; ++u) {
        float4 vv = ((const float4*)a)[t + u * 256];
        vv.x *= scale; vv.y *= scale; vv.z *= scale; vv.w *= scale;
        vals[u] = vv;
        mx = fmaxf(mx, fmaxf(fmaxf(vv.x, vv.y), fmaxf(vv.z, vv.w)));
    }
    __shared__ float red[4];
    #pragma unroll
    for (int off = 32; off > 0; off >>= 1) mx = fmaxf(mx, __shfl_down(mx, off));
    if ((t & 63) == 0) red[t >> 6] = mx;
    __syncthreads();
    const float m = fmaxf(fmaxf(red[0], red[1]), fmaxf(red[2], red[3]));
    __syncthreads();
    float sum = 0.f;
    #pragma unroll
    for (int u = 0; u < 4; ++u) {
        vals[u].x = __expf(vals[u].x - m);
        vals[u].y = __expf(vals[u].y - m);
        vals[u].z = __expf(vals[u].z - m);
        vals[u].w = __expf(vals[u].w - m);
        sum += vals[u].x + vals[u].y + vals[u].z + vals[u].w;
    }
    #pragma unroll
    for (int off = 32; off > 0; off >>= 1) sum += __shfl_down(sum, off);
    if ((t & 63) == 0) red[t >> 6] = sum;
    __syncthreads();
    const float inv = 1.f / (red[0] + red[1] + red[2] + red[3]);
    #pragma unroll
    for (int u = 0; u < 4; ++u) {
        ushort4v o;
        o[0] = f2bf(vals[u].x * inv);
        o[1] = f2bf(vals[u].y * inv);
        o[2] = f2bf(vals[u].z * inv);
        o[3] = f2bf(vals[u].w * inv);
        ((ushort4v*)p)[t + u * 256] = o;
    }
}

__global__ void edge_coeff_kernel(
    const int* __restrict__ ei, const float* __restrict__ attr,
    const ushort_t* __restrict__ P, float* __restrict__ c0, float* __restrict__ c1,
    int E, int N, const float* __restrict__ ibp, const float* __restrict__ imp)
{
    const int e = blockIdx.x * blockDim.x + threadIdx.x;
    if (e >= E) return;
    const int src = ei[e];
    const int dst = ei[E + e];
    const float s = 1.f / (1.f + __expf(-(attr[e] - ibp[0]) * imp[0]));
    const float pv = bf2f(P[(size_t)src * N + dst]);
    atomicAdd(&c0[src], pv * s);
    atomicAdd(&c1[src], pv * (1.f - s));
}

// out = sum_z parts[z] + c0[i]*Ev0 + c1[i]*Ev1  (float4-vectorized)
__global__ void reduce_add_rv_kernel(
    const float* __restrict__ parts, float* __restrict__ out,
    const float* __restrict__ c0, const float* __restrict__ c1,
    const float* __restrict__ Ev, int FEAT, size_t zstride, int nz)
{
    const int i4 = blockIdx.x * 256 + threadIdx.x;   // float4 index
    const int F4 = FEAT / 4;
    const int node = i4 / F4;
    const int f4 = i4 % F4;
    float4 acc = ((const float4*)parts)[i4];
    for (int z = 1; z < nz; ++z) {
        const float4 p = *(const float4*)(parts + (size_t)z * zstride + (size_t)i4 * 4);
        acc.x += p.x; acc.y += p.y; acc.z += p.z; acc.w += p.w;
    }
    const float a0 = c0[node], a1 = c1[node];
    const float4 e0 = ((const float4*)Ev)[f4];
    const float4 e1 = ((const float4*)Ev)[F4 + f4];
    acc.x += a0 * e0.x + a1 * e1.x;
    acc.y += a0 * e0.y + a1 * e1.y;
    acc.z += a0 * e0.z + a1 * e1.z;
    acc.w += a0 * e0.w + a1 * e1.w;
    ((float4*)out)[i4] = acc;
}

// ---------------------------------------------------------------------------
extern "C" void kernel_launch(void* const* d_in, const int* in_sizes, int n_in,
                              void* d_out, int out_size, void* d_ws, size_t ws_size,
                              hipStream_t stream)
{
    const float* x    = (const float*)d_in[0];
    const int*   ei   = (const int*)d_in[1];
    const float* attr = (const float*)d_in[2];
    const float* Wk   = (const float*)d_in[3];
    const float* Wq   = (const float*)d_in[4];
    const float* Wv   = (const float*)d_in[5];
    const float* Ek   = (const float*)d_in[6];
    const float* Eq   = (const float*)d_in[7];
    const float* Ev   = (const float*)d_in[8];
    const float* ib   = (const float*)d_in[9];
    const float* im   = (const float*)d_in[10];
    float* out = (float*)d_out;

    const int FEAT = (int)lroundf(sqrtf((float)in_sizes[5]));   // 512
    const int HID  = in_sizes[3] / FEAT;                        // 256
    const int N    = in_sizes[0] / FEAT;                        // 4096
    const int E    = in_sizes[2];                               // 131072

    char* w = (char*)d_ws;
    size_t o = 0;
    ushort_t* xb   = (ushort_t*)(w + o); o += (size_t)N * FEAT * 2;
    ushort_t* Wqkt = (ushort_t*)(w + o); o += (size_t)2 * HID * FEAT * 2;
    ushort_t* Wvt  = (ushort_t*)(w + o); o += (size_t)FEAT * FEAT * 2;
    ushort_t* qkb  = (ushort_t*)(w + o); o += (size_t)N * 2 * HID * 2;
    ushort_t* vTb  = (ushort_t*)(w + o); o += (size_t)FEAT * N * 2;
    float*    Abuf = (float*)(w + o);    o += (size_t)N * N * 4;
    ushort_t* Pb   = (ushort_t*)(w + o); o += (size_t)N * N * 2;
    float*    qk0  = (float*)(w + o);    o += (size_t)N * 4;
    float*    qk1  = (float*)(w + o);    o += (size_t)N * 4;
    float*    kq0  = (float*)(w + o);    o += (size_t)N * 4;
    float*    kq1  = (float*)(w + o);    o += (size_t)N * 4;
    float*    c0   = (float*)(w + o);    o += (size_t)N * 4;
    float*    c1   = (float*)(w + o);    o += (size_t)N * 4;
    float*    pvpart = Abuf;   // logits dead after softmax; 4 x 8 MB fits in 64 MB

    const dim3 blk(256);
    const int NZ = 4;
    const int Kchunk = N / NZ;         // 1024

    // prep: x->bf16 + weight transposes (one launch)
    const int prepBlocks = (N * FEAT / 8) / 256 + 2 * ((HID * FEAT) / 256)
                         + (FEAT * FEAT) / 256;
    prep_kernel<<<prepBlocks, blk, 0, stream>>>(x, Wq, Wk, Wv, xb, Wqkt, Wvt,
                                                N, FEAT, HID);

    // both projections, one launch (256 blocks)
    proj_gemm<<<256, blk, 0, stream>>>(xb, Wqkt, Wvt, qkb, vTb, FEAT, HID, N);

    // per-node embedding dots (+ c0/c1 zero)
    node_dots<<<N, blk, 0, stream>>>(qkb, Ek, Eq, qk0, qk1, kq0, kq1, c0, c1, HID);

    // A = 2 * q k^T  (f32)
    gemm_nt_mfma<false><<<dim3(N / 128, N / 128), blk, 0, stream>>>(
        qkb, qkb + HID, Abuf, 2 * HID, 2 * HID, N, HID, 2.f, 0);

    // += per-edge bias
    edge_bias_kernel<<<(E + 255) / 256, blk, 0, stream>>>(ei, attr, qk0, qk1, kq0, kq1,
                                                          Abuf, E, N, ib, im);

    // P = softmax(A / sqrt(FEAT)) -> bf16
    softmax_rows_bf16<<<N, blk, 0, stream>>>(Abuf, Pb, N, 1.f / sqrtf((float)FEAT));

    // edge coefficients
    edge_coeff_kernel<<<(E + 255) / 256, blk, 0, stream>>>(ei, attr, Pb, c0, c1, E, N, ib, im);

    // PV partials: pvpart[z] = P[:, zK:(z+1)K] @ v[zK:(z+1)K, :]
    gemm_nt_mfma<false><<<dim3(FEAT / 128, N / 128, NZ), blk, 0, stream>>>(
        Pb, vTb, pvpart, N, N, FEAT, Kchunk, 1.f, (size_t)N * FEAT);

    // out = sum_z partials + c0[i]*Ev0 + c1[i]*Ev1
    reduce_add_rv_kernel<<<(N * FEAT / 4 + 255) / 256, blk, 0, stream>>>(
        pvpart, out, c0, c1, Ev, FEAT, (size_t)N * FEAT, NZ);
}